// Round 8
// baseline (148.795 us; speedup 1.0000x reference)
//
#include <hip/hip_runtime.h>
#include <stdint.h>

#define DEVFN __device__ __forceinline__

typedef __attribute__((ext_vector_type(8))) __bf16 bf16x8;
typedef __attribute__((ext_vector_type(8))) short short8;
typedef __attribute__((ext_vector_type(4))) float f32x4;

DEVFN unsigned short f2bf(float f) {
  union { float f; unsigned u; } v; v.f = f;
  return (unsigned short)((v.u + 0x7FFFu + ((v.u >> 16) & 1u)) >> 16);
}

// global -> LDS direct copy, 16B per lane. Dest must be linear in lane order.
DEVFN void gload_lds16(const void* g, void* l) {
  __builtin_amdgcn_global_load_lds(
      (const __attribute__((address_space(1))) void*)(uintptr_t)g,
      (__attribute__((address_space(3))) void*)(uint32_t)(uintptr_t)l,
      16, 0, 0);
}

// ---------------- prep kernels ----------------

__global__ void k_cast_x(const float* __restrict__ x, short* __restrict__ xb, int n8) {
  int i = blockIdx.x * blockDim.x + threadIdx.x;
  if (i >= n8) return;
  const f32x4* xf = (const f32x4*)x;
  f32x4 a = xf[2 * i], b = xf[2 * i + 1];
  short8 s;
  s[0] = (short)f2bf(a[0]); s[1] = (short)f2bf(a[1]);
  s[2] = (short)f2bf(a[2]); s[3] = (short)f2bf(a[3]);
  s[4] = (short)f2bf(b[0]); s[5] = (short)f2bf(b[1]);
  s[6] = (short)f2bf(b[2]); s[7] = (short)f2bf(b[3]);
  ((short8*)xb)[i] = s;
}

// w[R][C] (f32) -> wt[C][R] (bf16)
__global__ void k_transpose_bf(const float* __restrict__ w, short* __restrict__ wt, int R, int C) {
  int i = blockIdx.x * blockDim.x + threadIdx.x;
  if (i >= R * C) return;
  int c = i / R, r = i - c * R;
  wt[i] = (short)f2bf(w[(size_t)r * C + c]);
}

// ---------------- GEMM: C[M][N] = A[M][K] * Bt[N][K]^T ----------------
// Block tile 128 x (NB*32), BK=32, 256 threads (4 waves), per-wave 64 x (NB*16).
// NB=8 (GEMM1): 12 ds_read per 32 MFMA/wave-step = 43.7 FLOP/LDS-byte.
// NB=4 (GEMM2): the verified 128x128 structure.
// 3-buffer pipeline, counted vmcnt; T1 XCD swizzle; T2 slot-swizzle.

template <int BF16_OUT, int NB>
__global__ __launch_bounds__(256, NB == 8 ? 2 : 3)
void k_gemm(const short* __restrict__ A, const short* __restrict__ Bt,
            unsigned short* __restrict__ Cb, float* __restrict__ Cf,
            const float* __restrict__ bias, int M, int N, int K) {
  constexpr int BN = NB * 32;          // 256 or 128
  constexpr int BCH = NB / 2;          // B staging chunks per thread (4 or 2)
  __shared__ short As[3][128 * 32];
  __shared__ short Bs[3][BN * 32];
  const int tid = threadIdx.x;
  const int l = tid & 63, w = tid >> 6;
  const int ntile = N / BN;
  // XCD-chunked swizzle (T1): grid % 8 == 0 (1536 / 768).
  const int nwg = gridDim.x, cpx = nwg >> 3;
  const int bid = (blockIdx.x & 7) * cpx + (blockIdx.x >> 3);
  const int mt = bid / ntile, nt = bid % ntile;
  const int m0 = mt << 7, n0 = nt * BN;
  const int wm = (w >> 1) << 6, wn = (w & 1) * (NB * 16);

  f32x4 acc[4][NB];
#pragma unroll
  for (int i = 0; i < 4; i++)
#pragma unroll
    for (int j = 0; j < NB; j++) acc[i][j] = (f32x4){0.f, 0.f, 0.f, 0.f};

  const int nsteps = K >> 5;  // 12 (GEMM1) or 16 (GEMM2)

  auto stage = [&](int buf, int t) {
#pragma unroll
    for (int c = 0; c < 2; ++c) {
      int ch = tid + c * 256;
      int row = ch >> 2;
      int sl = (ch & 3) ^ ((row >> 1) & 3);  // inverse-swizzled source slot
      gload_lds16(A + (size_t)(m0 + row) * K + t * 32 + sl * 8, &As[buf][ch * 8]);
    }
#pragma unroll
    for (int c = 0; c < BCH; ++c) {
      int ch = tid + c * 256;
      int row = ch >> 2;
      int sl = (ch & 3) ^ ((row >> 1) & 3);
      gload_lds16(Bt + (size_t)(n0 + row) * K + t * 32 + sl * 8, &Bs[buf][ch * 8]);
    }
  };
  // swizzled read slot: rows base+(l&15), base%16==0 -> (row>>1)&3 == (l>>1)&3
  const int sp8 = (((l >> 4) ^ ((l >> 1) & 3)) << 3);
  auto compute = [&](int buf) {
    bf16x8 af[4], bfr[NB];
#pragma unroll
    for (int i = 0; i < 4; i++)
      af[i] = *(const bf16x8*)&As[buf][(wm + i * 16 + (l & 15)) * 32 + sp8];
#pragma unroll
    for (int j = 0; j < NB; j++)
      bfr[j] = *(const bf16x8*)&Bs[buf][(wn + j * 16 + (l & 15)) * 32 + sp8];
#pragma unroll
    for (int i = 0; i < 4; i++)
#pragma unroll
      for (int j = 0; j < NB; j++)
        acc[i][j] = __builtin_amdgcn_mfma_f32_16x16x32_bf16(af[i], bfr[j], acc[i][j], 0, 0, 0);
  };

  // prologue: 2 tiles in flight ((2+BCH) gload_lds16 each per thread)
  stage(0, 0);
  stage(1, 1);
#pragma unroll 1
  for (int t = 0; t < nsteps; ++t) {
    // wait for tile-t's (2+BCH) loads; keep tile-(t+1)'s in flight
    if (t + 1 < nsteps) {
      if constexpr (NB == 8)
        asm volatile("s_waitcnt vmcnt(6)" ::: "memory");
      else
        asm volatile("s_waitcnt vmcnt(4)" ::: "memory");
    } else {
      asm volatile("s_waitcnt vmcnt(0)" ::: "memory");
    }
    __builtin_amdgcn_sched_barrier(0);
    __builtin_amdgcn_s_barrier();  // all waves' t-loads done; all done reading buf[t-1]
    __builtin_amdgcn_sched_barrier(0);
    if (t + 2 < nsteps) stage((t + 2) % 3, t + 2);  // overwrites buf[(t-1)%3]: safe post-barrier
    compute(t % 3);
  }

#pragma unroll
  for (int i = 0; i < 4; i++) {
    int mrow = m0 + wm + i * 16 + ((l >> 4) << 2);
#pragma unroll
    for (int j = 0; j < NB; j++) {
      int ncol = n0 + wn + j * 16 + (l & 15);
#pragma unroll
      for (int r = 0; r < 4; r++) {
        if (BF16_OUT) {
          Cb[(size_t)(mrow + r) * N + ncol] = f2bf(acc[i][j][r]);
        } else {
          Cf[(size_t)(mrow + r) * N + ncol] = acc[i][j][r] + bias[ncol];
        }
      }
    }
  }
}

// ---------------- fused attention per (bp, head) ----------------
// qkv[token][1536]: Q at h*64, K at 512+h*64, V at 1024+h*64 (bf16).
// 512 threads = 8 waves; wave w handles q rows [w*32, w*32+32) in 2 iters of 16.
// __launch_bounds__(512, 4): without it hipcc budgets 64 VGPRs (default
// 1024-thread assumption) and spills s[16] -> ~29 MB scratch writes/dispatch
// (measured WRITE 62.9 MB vs 33.5 MB legit). 4 waves/SIMD = 2 blocks/CU
// (same occupancy as measured) with a 128-VGPR budget.

__global__ __launch_bounds__(512, 4)
void k_attn(const short* __restrict__ qkv, unsigned short* __restrict__ O) {
  __shared__ short Kl[256 * 64];        // [kcol][64d], XOR-swizzled 16B slots
  __shared__ short Vt[64 * 256];        // [d][256k], XOR-swizzled 16B slots
  __shared__ short Pc[8][16 * 40];      // per-wave P chunk [16q][32k] padded to 40

  const int tid = threadIdx.x, l = tid & 63, w = tid >> 6;
  const int bh = blockIdx.x;
  const int bp = bh >> 3, h = bh & 7;
  const size_t tokbase = (size_t)bp * 256 * 1536;
  const int qoff = h * 64, koff = 512 + h * 64, voff = 1024 + h * 64;

  // stage K: linear LDS dest, inverse-swizzled global source (slot ^= row&7)
#pragma unroll
  for (int c = 0; c < 4; ++c) {
    int ch = tid + c * 512;
    int row = ch >> 3, s = ch & 7;
    int sg = s ^ (row & 7);
    gload_lds16(qkv + tokbase + (size_t)row * 1536 + koff + sg * 8, &Kl[ch * 8]);
  }
  // stage V transposed: Vt[d][k], 16B slot' = (k/8) ^ (d&15)
#pragma unroll
  for (int c = 0; c < 4; ++c) {
    int ch = tid + c * 512;
    int row = ch >> 3, d0 = (ch & 7) * 8;
    short8 v = *(const short8*)(qkv + tokbase + (size_t)row * 1536 + voff + d0);
#pragma unroll
    for (int j = 0; j < 8; ++j) {
      int d = d0 + j;
      Vt[d * 256 + (((((row >> 3) ^ (d & 15))) << 3) | (row & 7))] = v[j];
    }
  }
  __syncthreads();

  const float CEXP = 0.125f * 1.44269504f;  // SCALE * log2(e)

#pragma unroll 1
  for (int it = 0; it < 2; ++it) {
    const int q0 = w * 32 + it * 16;
    bf16x8 qa[2];
#pragma unroll
    for (int dc = 0; dc < 2; ++dc)
      qa[dc] = *(const bf16x8*)(qkv + tokbase + (size_t)(q0 + (l & 15)) * 1536 + qoff +
                                dc * 32 + (l >> 4) * 8);
    // S = Q K^T  (C layout: row=q=(l>>4)*4+r, col=k=l&15 within 16-tile)
    f32x4 s[16];
#pragma unroll
    for (int kt = 0; kt < 16; kt++) s[kt] = (f32x4){0.f, 0.f, 0.f, 0.f};
#pragma unroll
    for (int dc = 0; dc < 2; ++dc) {
#pragma unroll
      for (int kt = 0; kt < 16; ++kt) {
        int kcol = kt * 16 + (l & 15);
        int sl = (dc * 4 + (l >> 4)) ^ (kcol & 7);
        bf16x8 kb = *(const bf16x8*)&Kl[kcol * 64 + sl * 8];
        s[kt] = __builtin_amdgcn_mfma_f32_16x16x32_bf16(qa[dc], kb, s[kt], 0, 0, 0);
      }
    }
    // softmax over k (unnormalized P; 1/sum folded into epilogue)
    float rs[4];
#pragma unroll
    for (int r = 0; r < 4; ++r) {
      float m = s[0][r];
#pragma unroll
      for (int kt = 1; kt < 16; kt++) m = fmaxf(m, s[kt][r]);
      for (int off = 1; off < 16; off <<= 1) m = fmaxf(m, __shfl_xor(m, off, 64));
      float sum = 0.f;
#pragma unroll
      for (int kt = 0; kt < 16; kt++) {
        float p = exp2f((s[kt][r] - m) * CEXP);
        s[kt][r] = p;
        sum += p;
      }
      for (int off = 1; off < 16; off <<= 1) sum += __shfl_xor(sum, off, 64);
      rs[r] = 1.0f / sum;
    }
    // PV: chunk P (16q x 32k) through per-wave LDS, MFMA into O.
    // Fully unrolled (rule #20): runtime kc index would force s[] to scratch.
    f32x4 o[4];
#pragma unroll
    for (int dt = 0; dt < 4; dt++) o[dt] = (f32x4){0.f, 0.f, 0.f, 0.f};
    short* pc = &Pc[w][0];
#pragma unroll
    for (int kc = 0; kc < 8; ++kc) {
#pragma unroll
      for (int t2 = 0; t2 < 2; ++t2) {
        int kt = kc * 2 + t2;
#pragma unroll
        for (int r = 0; r < 4; ++r)
          pc[((l >> 4) * 4 + r) * 40 + t2 * 16 + (l & 15)] = (short)f2bf(s[kt][r]);
      }
      asm volatile("" ::: "memory");  // keep write->read program order (per-wave DS is in-order)
      bf16x8 pa = *(const bf16x8*)&pc[(l & 15) * 40 + (l >> 4) * 8];
#pragma unroll
      for (int dt = 0; dt < 4; ++dt) {
        int d = dt * 16 + (l & 15);
        int sl = (kc * 4 + (l >> 4)) ^ (d & 15);
        bf16x8 vb = *(const bf16x8*)&Vt[d * 256 + sl * 8];
        o[dt] = __builtin_amdgcn_mfma_f32_16x16x32_bf16(pa, vb, o[dt], 0, 0, 0);
      }
      asm volatile("" ::: "memory");
    }
    // epilogue: scale by 1/sum, store bf16 O[token][h*64+d]
#pragma unroll
    for (int dt = 0; dt < 4; dt++) {
#pragma unroll
      for (int r = 0; r < 4; r++) {
        int qrow = q0 + ((l >> 4) << 2) + r;
        int d = dt * 16 + (l & 15);
        O[(size_t)(bp * 256 + qrow) * 512 + h * 64 + d] = f2bf(o[dt][r] * rs[r]);
      }
    }
  }
}

// ---------------- launch ----------------

extern "C" void kernel_launch(void* const* d_in, const int* in_sizes, int n_in,
                              void* d_out, int out_size, void* d_ws, size_t ws_size,
                              hipStream_t stream) {
  const float* x    = (const float*)d_in[0];
  const float* wqkv = (const float*)d_in[1];
  const float* wout = (const float*)d_in[2];
  const float* bout = (const float*)d_in[3];
  float* out = (float*)d_out;
  char* ws = (char*)d_ws;

  // ws layout (O overlaps Xb/Wqt, which are dead after GEMM1): total ~134.6 MB
  short* Wot = (short*)(ws);                          //   0.39 MB [384][512]
  short* Xb  = (short*)(ws + 393216);                 //  25.17 MB [32768][384]
  short* Wqt = (short*)(ws + 25559040);               //   1.18 MB [1536][384]
  unsigned short* O = (unsigned short*)(ws + 393216); //  33.55 MB [32768][512]
  short* QKV = (short*)(ws + 33947648);               // 100.66 MB [32768][1536]

  k_cast_x<<<6144, 256, 0, stream>>>(x, Xb, 1572864);
  k_transpose_bf<<<2304, 256, 0, stream>>>(wqkv, Wqt, 384, 1536);
  k_transpose_bf<<<768, 256, 0, stream>>>(wout, Wot, 512, 384);
  // GEMM1: 128x256 tiles -> (32768/128)*(1536/256) = 1536 blocks (%8==0)
  k_gemm<1, 8><<<1536, 256, 0, stream>>>(Xb, Wqt, (unsigned short*)QKV, nullptr, nullptr,
                                         32768, 1536, 384);
  k_attn<<<1024, 512, 0, stream>>>(QKV, O);
  // GEMM2: 128x128 tiles -> (32768/128)*(384/128) = 768 blocks (%8==0)
  k_gemm<0, 4><<<768, 256, 0, stream>>>((const short*)O, Wot, nullptr, out, bout,
                                        32768, 384, 512);
  (void)in_sizes; (void)n_in; (void)out_size; (void)ws_size;
}

// Round 9
// 143.068 us; speedup vs baseline: 1.0400x; 1.0400x over previous
//
#include <hip/hip_runtime.h>
#include <stdint.h>

#define DEVFN __device__ __forceinline__

typedef __attribute__((ext_vector_type(8))) __bf16 bf16x8;
typedef __attribute__((ext_vector_type(8))) short short8;
typedef __attribute__((ext_vector_type(4))) float f32x4;

DEVFN unsigned short f2bf(float f) {
  union { float f; unsigned u; } v; v.f = f;
  return (unsigned short)((v.u + 0x7FFFu + ((v.u >> 16) & 1u)) >> 16);
}

// global -> LDS direct copy, 16B per lane. Dest must be linear in lane order.
DEVFN void gload_lds16(const void* g, void* l) {
  __builtin_amdgcn_global_load_lds(
      (const __attribute__((address_space(1))) void*)(uintptr_t)g,
      (__attribute__((address_space(3))) void*)(uint32_t)(uintptr_t)l,
      16, 0, 0);
}

// ---------------- prep kernels ----------------

__global__ void k_cast_x(const float* __restrict__ x, short* __restrict__ xb, int n8) {
  int i = blockIdx.x * blockDim.x + threadIdx.x;
  if (i >= n8) return;
  const f32x4* xf = (const f32x4*)x;
  f32x4 a = xf[2 * i], b = xf[2 * i + 1];
  short8 s;
  s[0] = (short)f2bf(a[0]); s[1] = (short)f2bf(a[1]);
  s[2] = (short)f2bf(a[2]); s[3] = (short)f2bf(a[3]);
  s[4] = (short)f2bf(b[0]); s[5] = (short)f2bf(b[1]);
  s[6] = (short)f2bf(b[2]); s[7] = (short)f2bf(b[3]);
  ((short8*)xb)[i] = s;
}

// w[R][C] (f32) -> wt[C][R] (bf16)
__global__ void k_transpose_bf(const float* __restrict__ w, short* __restrict__ wt, int R, int C) {
  int i = blockIdx.x * blockDim.x + threadIdx.x;
  if (i >= R * C) return;
  int c = i / R, r = i - c * R;
  wt[i] = (short)f2bf(w[(size_t)r * C + c]);
}

// ---------------- GEMM: C[M][N] = A[M][K] * Bt[N][K]^T ----------------
// Block tile 128 x (NB*32), BK=32, 256 threads (4 waves), per-wave 64 x (NB*16).
// NB=8 (GEMM1): 12 ds_read per 32 MFMA/wave-step = 43.7 FLOP/LDS-byte.
// NB=4 (GEMM2): the verified 128x128 structure.
// 3-buffer pipeline, counted vmcnt; T1 XCD swizzle; T2 slot-swizzle.

template <int BF16_OUT, int NB>
__global__ __launch_bounds__(256, NB == 8 ? 2 : 3)
void k_gemm(const short* __restrict__ A, const short* __restrict__ Bt,
            unsigned short* __restrict__ Cb, float* __restrict__ Cf,
            const float* __restrict__ bias, int M, int N, int K) {
  constexpr int BN = NB * 32;          // 256 or 128
  constexpr int BCH = NB / 2;          // B staging chunks per thread (4 or 2)
  __shared__ short As[3][128 * 32];
  __shared__ short Bs[3][BN * 32];
  const int tid = threadIdx.x;
  const int l = tid & 63, w = tid >> 6;
  const int ntile = N / BN;
  // XCD-chunked swizzle (T1): grid % 8 == 0 (1536 / 768).
  const int nwg = gridDim.x, cpx = nwg >> 3;
  const int bid = (blockIdx.x & 7) * cpx + (blockIdx.x >> 3);
  const int mt = bid / ntile, nt = bid % ntile;
  const int m0 = mt << 7, n0 = nt * BN;
  const int wm = (w >> 1) << 6, wn = (w & 1) * (NB * 16);

  f32x4 acc[4][NB];
#pragma unroll
  for (int i = 0; i < 4; i++)
#pragma unroll
    for (int j = 0; j < NB; j++) acc[i][j] = (f32x4){0.f, 0.f, 0.f, 0.f};

  const int nsteps = K >> 5;  // 12 (GEMM1) or 16 (GEMM2)

  auto stage = [&](int buf, int t) {
#pragma unroll
    for (int c = 0; c < 2; ++c) {
      int ch = tid + c * 256;
      int row = ch >> 2;
      int sl = (ch & 3) ^ ((row >> 1) & 3);  // inverse-swizzled source slot
      gload_lds16(A + (size_t)(m0 + row) * K + t * 32 + sl * 8, &As[buf][ch * 8]);
    }
#pragma unroll
    for (int c = 0; c < BCH; ++c) {
      int ch = tid + c * 256;
      int row = ch >> 2;
      int sl = (ch & 3) ^ ((row >> 1) & 3);
      gload_lds16(Bt + (size_t)(n0 + row) * K + t * 32 + sl * 8, &Bs[buf][ch * 8]);
    }
  };
  // swizzled read slot: rows base+(l&15), base%16==0 -> (row>>1)&3 == (l>>1)&3
  const int sp8 = (((l >> 4) ^ ((l >> 1) & 3)) << 3);
  auto compute = [&](int buf) {
    bf16x8 af[4], bfr[NB];
#pragma unroll
    for (int i = 0; i < 4; i++)
      af[i] = *(const bf16x8*)&As[buf][(wm + i * 16 + (l & 15)) * 32 + sp8];
#pragma unroll
    for (int j = 0; j < NB; j++)
      bfr[j] = *(const bf16x8*)&Bs[buf][(wn + j * 16 + (l & 15)) * 32 + sp8];
#pragma unroll
    for (int i = 0; i < 4; i++)
#pragma unroll
      for (int j = 0; j < NB; j++)
        acc[i][j] = __builtin_amdgcn_mfma_f32_16x16x32_bf16(af[i], bfr[j], acc[i][j], 0, 0, 0);
  };

  // prologue: 2 tiles in flight ((2+BCH) gload_lds16 each per thread)
  stage(0, 0);
  stage(1, 1);
#pragma unroll 1
  for (int t = 0; t < nsteps; ++t) {
    // wait for tile-t's (2+BCH) loads; keep tile-(t+1)'s in flight
    if (t + 1 < nsteps) {
      if constexpr (NB == 8)
        asm volatile("s_waitcnt vmcnt(6)" ::: "memory");
      else
        asm volatile("s_waitcnt vmcnt(4)" ::: "memory");
    } else {
      asm volatile("s_waitcnt vmcnt(0)" ::: "memory");
    }
    __builtin_amdgcn_sched_barrier(0);
    __builtin_amdgcn_s_barrier();  // all waves' t-loads done; all done reading buf[t-1]
    __builtin_amdgcn_sched_barrier(0);
    if (t + 2 < nsteps) stage((t + 2) % 3, t + 2);  // overwrites buf[(t-1)%3]: safe post-barrier
    compute(t % 3);
  }

#pragma unroll
  for (int i = 0; i < 4; i++) {
    int mrow = m0 + wm + i * 16 + ((l >> 4) << 2);
#pragma unroll
    for (int j = 0; j < NB; j++) {
      int ncol = n0 + wn + j * 16 + (l & 15);
#pragma unroll
      for (int r = 0; r < 4; r++) {
        if (BF16_OUT) {
          Cb[(size_t)(mrow + r) * N + ncol] = f2bf(acc[i][j][r]);
        } else {
          Cf[(size_t)(mrow + r) * N + ncol] = acc[i][j][r] + bias[ncol];
        }
      }
    }
  }
}

// ---------------- fused attention per (bp, head) ----------------
// qkv[token][1536]: Q at h*64, K at 512+h*64, V at 1024+h*64 (bf16).
// 512 threads = 8 waves; wave w handles q rows [w*32, w*32+32) in 2 iters of 16.
// __launch_bounds__(512, 2): round-8 measurement showed the 2nd arg acts as
// MIN BLOCKS/CU on this toolchain (arg=4 -> 32 waves/CU -> 64-VGPR cap ->
// s[16] spilled, 52 MB excess scratch writes). LDS (75.8KB) caps residency
// at 2 blocks/CU anyway, so request exactly 2 -> 128-VGPR budget, which fits
// the ~115-reg live set spill-free at unchanged occupancy.

__global__ __launch_bounds__(512, 2)
void k_attn(const short* __restrict__ qkv, unsigned short* __restrict__ O) {
  __shared__ short Kl[256 * 64];        // [kcol][64d], XOR-swizzled 16B slots
  __shared__ short Vt[64 * 256];        // [d][256k], XOR-swizzled 16B slots
  __shared__ short Pc[8][16 * 40];      // per-wave P chunk [16q][32k] padded to 40

  const int tid = threadIdx.x, l = tid & 63, w = tid >> 6;
  const int bh = blockIdx.x;
  const int bp = bh >> 3, h = bh & 7;
  const size_t tokbase = (size_t)bp * 256 * 1536;
  const int qoff = h * 64, koff = 512 + h * 64, voff = 1024 + h * 64;

  // stage K: linear LDS dest, inverse-swizzled global source (slot ^= row&7)
#pragma unroll
  for (int c = 0; c < 4; ++c) {
    int ch = tid + c * 512;
    int row = ch >> 3, s = ch & 7;
    int sg = s ^ (row & 7);
    gload_lds16(qkv + tokbase + (size_t)row * 1536 + koff + sg * 8, &Kl[ch * 8]);
  }
  // stage V transposed: Vt[d][k], 16B slot' = (k/8) ^ (d&15)
#pragma unroll
  for (int c = 0; c < 4; ++c) {
    int ch = tid + c * 512;
    int row = ch >> 3, d0 = (ch & 7) * 8;
    short8 v = *(const short8*)(qkv + tokbase + (size_t)row * 1536 + voff + d0);
#pragma unroll
    for (int j = 0; j < 8; ++j) {
      int d = d0 + j;
      Vt[d * 256 + (((((row >> 3) ^ (d & 15))) << 3) | (row & 7))] = v[j];
    }
  }
  __syncthreads();

  const float CEXP = 0.125f * 1.44269504f;  // SCALE * log2(e)

#pragma unroll 1
  for (int it = 0; it < 2; ++it) {
    const int q0 = w * 32 + it * 16;
    bf16x8 qa[2];
#pragma unroll
    for (int dc = 0; dc < 2; ++dc)
      qa[dc] = *(const bf16x8*)(qkv + tokbase + (size_t)(q0 + (l & 15)) * 1536 + qoff +
                                dc * 32 + (l >> 4) * 8);
    // S = Q K^T  (C layout: row=q=(l>>4)*4+r, col=k=l&15 within 16-tile)
    f32x4 s[16];
#pragma unroll
    for (int kt = 0; kt < 16; kt++) s[kt] = (f32x4){0.f, 0.f, 0.f, 0.f};
#pragma unroll
    for (int dc = 0; dc < 2; ++dc) {
#pragma unroll
      for (int kt = 0; kt < 16; ++kt) {
        int kcol = kt * 16 + (l & 15);
        int sl = (dc * 4 + (l >> 4)) ^ (kcol & 7);
        bf16x8 kb = *(const bf16x8*)&Kl[kcol * 64 + sl * 8];
        s[kt] = __builtin_amdgcn_mfma_f32_16x16x32_bf16(qa[dc], kb, s[kt], 0, 0, 0);
      }
    }
    // softmax over k (unnormalized P; 1/sum folded into epilogue)
    float rs[4];
#pragma unroll
    for (int r = 0; r < 4; ++r) {
      float m = s[0][r];
#pragma unroll
      for (int kt = 1; kt < 16; kt++) m = fmaxf(m, s[kt][r]);
      for (int off = 1; off < 16; off <<= 1) m = fmaxf(m, __shfl_xor(m, off, 64));
      float sum = 0.f;
#pragma unroll
      for (int kt = 0; kt < 16; kt++) {
        float p = exp2f((s[kt][r] - m) * CEXP);
        s[kt][r] = p;
        sum += p;
      }
      for (int off = 1; off < 16; off <<= 1) sum += __shfl_xor(sum, off, 64);
      rs[r] = 1.0f / sum;
    }
    // PV: chunk P (16q x 32k) through per-wave LDS, MFMA into O.
    // Fully unrolled (rule #20): runtime kc index would force s[] to scratch.
    f32x4 o[4];
#pragma unroll
    for (int dt = 0; dt < 4; dt++) o[dt] = (f32x4){0.f, 0.f, 0.f, 0.f};
    short* pc = &Pc[w][0];
#pragma unroll
    for (int kc = 0; kc < 8; ++kc) {
#pragma unroll
      for (int t2 = 0; t2 < 2; ++t2) {
        int kt = kc * 2 + t2;
#pragma unroll
        for (int r = 0; r < 4; ++r)
          pc[((l >> 4) * 4 + r) * 40 + t2 * 16 + (l & 15)] = (short)f2bf(s[kt][r]);
      }
      asm volatile("" ::: "memory");  // keep write->read program order (per-wave DS is in-order)
      bf16x8 pa = *(const bf16x8*)&pc[(l & 15) * 40 + (l >> 4) * 8];
#pragma unroll
      for (int dt = 0; dt < 4; ++dt) {
        int d = dt * 16 + (l & 15);
        int sl = (kc * 4 + (l >> 4)) ^ (d & 15);
        bf16x8 vb = *(const bf16x8*)&Vt[d * 256 + sl * 8];
        o[dt] = __builtin_amdgcn_mfma_f32_16x16x32_bf16(pa, vb, o[dt], 0, 0, 0);
      }
      asm volatile("" ::: "memory");
    }
    // epilogue: scale by 1/sum, store bf16 O[token][h*64+d]
#pragma unroll
    for (int dt = 0; dt < 4; dt++) {
#pragma unroll
      for (int r = 0; r < 4; r++) {
        int qrow = q0 + ((l >> 4) << 2) + r;
        int d = dt * 16 + (l & 15);
        O[(size_t)(bp * 256 + qrow) * 512 + h * 64 + d] = f2bf(o[dt][r] * rs[r]);
      }
    }
  }
}

// ---------------- launch ----------------

extern "C" void kernel_launch(void* const* d_in, const int* in_sizes, int n_in,
                              void* d_out, int out_size, void* d_ws, size_t ws_size,
                              hipStream_t stream) {
  const float* x    = (const float*)d_in[0];
  const float* wqkv = (const float*)d_in[1];
  const float* wout = (const float*)d_in[2];
  const float* bout = (const float*)d_in[3];
  float* out = (float*)d_out;
  char* ws = (char*)d_ws;

  // ws layout (O overlaps Xb/Wqt, which are dead after GEMM1): total ~134.6 MB
  short* Wot = (short*)(ws);                          //   0.39 MB [384][512]
  short* Xb  = (short*)(ws + 393216);                 //  25.17 MB [32768][384]
  short* Wqt = (short*)(ws + 25559040);               //   1.18 MB [1536][384]
  unsigned short* O = (unsigned short*)(ws + 393216); //  33.55 MB [32768][512]
  short* QKV = (short*)(ws + 33947648);               // 100.66 MB [32768][1536]

  k_cast_x<<<6144, 256, 0, stream>>>(x, Xb, 1572864);
  k_transpose_bf<<<2304, 256, 0, stream>>>(wqkv, Wqt, 384, 1536);
  k_transpose_bf<<<768, 256, 0, stream>>>(wout, Wot, 512, 384);
  // GEMM1: 128x256 tiles -> (32768/128)*(1536/256) = 1536 blocks (%8==0)
  k_gemm<1, 8><<<1536, 256, 0, stream>>>(Xb, Wqt, (unsigned short*)QKV, nullptr, nullptr,
                                         32768, 1536, 384);
  k_attn<<<1024, 512, 0, stream>>>(QKV, O);
  // GEMM2: 128x128 tiles -> (32768/128)*(384/128) = 768 blocks (%8==0)
  k_gemm<0, 4><<<768, 256, 0, stream>>>((const short*)O, Wot, nullptr, out, bout,
                                        32768, 384, 512);
  (void)in_sizes; (void)n_in; (void)out_size; (void)ws_size;
}